// Round 1
// 142.499 us; speedup vs baseline: 1.0191x; 1.0191x over previous
//
#include <hip/hip_runtime.h>

// VectorQuantizer: B=16,T=8192,D=64,K=1024
// out = [quantized 131072x64 f32][indices 131072 as f32]
// Round 9: break the latency serialization. VGPR=64 regalloc was forcing
// ds_read -> 6-deep mfma chain -> tracker fully serial per 16-code tile.
// Now: register double-buffer of W fragments across cbl (ds_read for cbl+2
// issued under cbl's MFMAs), explicit 2-chain MFMA interleave, setprio(1)
// around the MFMA cluster, nontemporal output stores.
#define MTOK  131072
#define DIMD  64
#define KCODE 1024
#define TPB   128        // tokens per block = 4 waves x 32 tokens

typedef __bf16 bf16x8 __attribute__((ext_vector_type(8)));
typedef float  f32x4  __attribute__((ext_vector_type(4)));

__device__ __forceinline__ f32x4 mfma16(bf16x8 a, bf16x8 b, f32x4 c) {
    return __builtin_amdgcn_mfma_f32_16x16x32_bf16(a, b, c, 0, 0, 0);
}

// async global->LDS, 16B/lane; LDS dest = wave-uniform base + lane*16
__device__ __forceinline__ void g2l16(const void* g, void* l) {
    __builtin_amdgcn_global_load_lds(
        (const __attribute__((address_space(1))) unsigned int*)g,
        (__attribute__((address_space(3))) unsigned int*)l, 16, 0, 0);
}

// ---- prep: pack W into MFMA-fragment order + e2 tables (r5-verified) ----
// wpk element offset = cb*2048 + win*512 + lane*8
// win: 0=hi d0-31, 1=hi d32-63, 2=lo d0-31, 3=lo d32-63
// lane=(q,m): frag = w[cb*16+m][(win&1)*32+q*8 ..+8]
__global__ __launch_bounds__(256) void prep_kernel(
    const float* __restrict__ w, __bf16* __restrict__ wpk,
    float* __restrict__ e2n, float* __restrict__ e2) {
    int b   = blockIdx.x;
    int tid = threadIdx.x;
    if (b < 64) {                       // pack blocks
        int cb  = b;
        int win = tid >> 6, lane = tid & 63;
        int q = lane >> 4, m = lane & 15;
        int k = cb * 16 + m;
        int d0 = (win & 1) * 32 + q * 8;
        const float* src = w + (size_t)k * DIMD + d0;
        float4 v0 = *(const float4*)(src);
        float4 v1 = *(const float4*)(src + 4);
        float f[8] = {v0.x, v0.y, v0.z, v0.w, v1.x, v1.y, v1.z, v1.w};
        bf16x8 o;
#pragma unroll
        for (int j = 0; j < 8; ++j) {
            __bf16 h = (__bf16)f[j];
            o[j] = (win < 2) ? h : (__bf16)(f[j] - (float)h);
        }
        *(bf16x8*)(wpk + ((size_t)(cb * 4 + win) * 64 + lane) * 8) = o;
    } else {                            // e2: one code/thread, exact r1 fma order
        int k2 = (b - 64) * 256 + tid;
        const float4* row = (const float4*)(w + (size_t)k2 * DIMD);
        float s = 0.f;
#pragma unroll
        for (int i = 0; i < 16; ++i) {
            float4 v = row[i];
            s = fmaf(v.x, v.x, s); s = fmaf(v.y, v.y, s);
            s = fmaf(v.z, v.z, s); s = fmaf(v.w, v.w, s);
        }
        e2[k2]  = s;
        e2n[k2] = -0.5f * s;
    }
}

__global__ __launch_bounds__(256, 4) void vq_main(
    const float* __restrict__ x, const float* __restrict__ wfull,
    const __bf16* __restrict__ wpk, const float* __restrict__ e2n_g,
    const float* __restrict__ e2_g, float* __restrict__ out) {

    // 2 x 16KB W chunk double-buffer + 4KB e2 = 36KB -> 4 blocks/CU
    __shared__ __align__(16) __bf16 ldsW[2][8192];
    __shared__ __align__(16) float  ldsE[KCODE];

    const int tid  = threadIdx.x;
    const int blk  = blockIdx.x;
    const int lane = tid & 63;
    const int wv   = tid >> 6;      // wave -> tokens wv*32..+32
    const int q    = lane >> 4;
    const int m    = lane & 15;
    const size_t tok0 = (size_t)blk * TPB + wv * 32;   // wave's first token

    // ---- issue async stage: chunk 0 (16KB) + e2 table (4KB) ----
    {
        const char* gw = (const char*)wpk + (size_t)wv * 4096 + (size_t)lane * 16;
        char* lw = (char*)&ldsW[0][0] + wv * 4096 + lane * 16;
#pragma unroll
        for (int j = 0; j < 4; ++j)
            g2l16(gw + j * 1024, lw + j * 1024);
        g2l16((const char*)e2n_g + (size_t)wv * 1024 + lane * 16,
              (char*)ldsE + wv * 1024 + lane * 16);
    }

    // ---- x fragments straight from global, hi/lo split in registers ----
    bf16x8 bx[2][4];
#pragma unroll
    for (int tg = 0; tg < 2; ++tg) {
        const float* xr = x + (tok0 + tg * 16 + m) * DIMD;
#pragma unroll
        for (int h = 0; h < 2; ++h) {
            float4 v0 = *(const float4*)(xr + h * 32 + q * 8);
            float4 v1 = *(const float4*)(xr + h * 32 + q * 8 + 4);
            float f[8] = {v0.x, v0.y, v0.z, v0.w, v1.x, v1.y, v1.z, v1.w};
            bf16x8 hi, lo;
#pragma unroll
            for (int j = 0; j < 8; ++j) {
                __bf16 hh = (__bf16)f[j];
                hi[j] = hh;
                lo[j] = (__bf16)(f[j] - (float)hh);
            }
            bx[tg][h]     = hi;
            bx[tg][2 + h] = lo;
        }
    }

    float b1[2], b2[2]; int i1[2];
#pragma unroll
    for (int tg = 0; tg < 2; ++tg) { b1[tg] = -3e38f; b2[tg] = -3e38f; i1[tg] = 0; }

    __syncthreads();   // chunk 0 + e2 resident (barrier drains vmcnt)

    // ---- main loop: 16 chunks x 64 codes; prefetch next chunk under compute.
    // Register pipeline: fragments for cbl+2 are ds_read while cbl computes,
    // so LDS latency and the 6-deep MFMA chains overlap with tracker VALU.
    for (int c = 0; c < 16; ++c) {
        const __bf16* wb = &ldsW[c & 1][0] + lane * 8;   // frag base; rest is imm
        const int eb = c * 64 + q * 4;

        bf16x8 A0[2], A1[2], A2[2], A3[2];
        f32x4  EE[2];

        // slot 0 <- cbl 0 (first use ~immediately; exposed once per chunk)
        A0[0] = *(const bf16x8*)(wb + 0);
        A1[0] = *(const bf16x8*)(wb + 512);
        A2[0] = *(const bf16x8*)(wb + 1024);
        A3[0] = *(const bf16x8*)(wb + 1536);
        EE[0] = *(const f32x4*)&ldsE[eb];

        if (c + 1 < 16) {                   // prefetch next chunk under compute
            const char* gw = (const char*)wpk + (size_t)(c + 1) * 16384
                           + (size_t)wv * 4096 + (size_t)lane * 16;
            char* lw = (char*)&ldsW[(c + 1) & 1][0] + wv * 4096 + lane * 16;
#pragma unroll
            for (int j = 0; j < 4; ++j)
                g2l16(gw + j * 1024, lw + j * 1024);
        }

        // slot 1 <- cbl 1
        A0[1] = *(const bf16x8*)(wb + 2048);
        A1[1] = *(const bf16x8*)(wb + 2048 + 512);
        A2[1] = *(const bf16x8*)(wb + 2048 + 1024);
        A3[1] = *(const bf16x8*)(wb + 2048 + 1536);
        EE[1] = *(const f32x4*)&ldsE[eb + 16];

#pragma unroll
        for (int cbl = 0; cbl < 4; ++cbl) {
            const int cur = cbl & 1;        // compile-time after unroll
            f32x4 t0, t1;
            // acc = dot - e2/2 (C-init); argmax(acc) == argmin(dist).
            // Two independent accumulator chains interleaved.
            __builtin_amdgcn_s_setprio(1);
            t0 = mfma16(A0[cur], bx[0][0], EE[cur]);   // w_hi*x_hi d0-31
            t1 = mfma16(A0[cur], bx[1][0], EE[cur]);
            t0 = mfma16(A1[cur], bx[0][1], t0);        // w_hi*x_hi d32-63
            t1 = mfma16(A1[cur], bx[1][1], t1);
            t0 = mfma16(A0[cur], bx[0][2], t0);        // w_hi*x_lo
            t1 = mfma16(A0[cur], bx[1][2], t1);
            t0 = mfma16(A1[cur], bx[0][3], t0);
            t1 = mfma16(A1[cur], bx[1][3], t1);
            t0 = mfma16(A2[cur], bx[0][0], t0);        // w_lo*x_hi
            t1 = mfma16(A2[cur], bx[1][0], t1);
            t0 = mfma16(A3[cur], bx[0][1], t0);
            t1 = mfma16(A3[cur], bx[1][1], t1);
            __builtin_amdgcn_s_setprio(0);

            if (cbl < 2) {                  // refill slot with cbl+2's frags;
                const int nx = cbl + 2;     // lands under next cbl's MFMAs
                A0[cur] = *(const bf16x8*)(wb + nx * 2048);
                A1[cur] = *(const bf16x8*)(wb + nx * 2048 + 512);
                A2[cur] = *(const bf16x8*)(wb + nx * 2048 + 1024);
                A3[cur] = *(const bf16x8*)(wb + nx * 2048 + 1536);
                EE[cur] = *(const f32x4*)&ldsE[eb + nx * 16];
            }

            // Tracker: top-1 (value+idx, strict > => ties keep lower code)
            // + top-2 value (med3). Same op order as verified r5 numerics.
            const int cbase = (c * 4 + cbl) * 16;
#pragma unroll
            for (int r = 0; r < 4; ++r) {
                float a  = t0[r];
                int iv   = cbase + q * 4 + r;
                bool gt  = a > b1[0];
                i1[0] = gt ? iv : i1[0];
                b2[0] = __builtin_amdgcn_fmed3f(a, b1[0], b2[0]);
                b1[0] = fmaxf(a, b1[0]);
            }
#pragma unroll
            for (int r = 0; r < 4; ++r) {
                float a  = t1[r];
                int iv   = cbase + q * 4 + r;
                bool gt  = a > b1[1];
                i1[1] = gt ? iv : i1[1];
                b2[1] = __builtin_amdgcn_fmed3f(a, b1[1], b2[1]);
                b1[1] = fmaxf(a, b1[1]);
            }
        }
        if (c + 1 < 16) __syncthreads();   // buf c&1 free; prefetch c+1 landed
    }

    // ---- cross-quad merge: lanes m,m+16,m+32,m+48 hold disjoint code sets ----
    float B1f[2], B2f[2]; int I1f[2];
#pragma unroll
    for (int tg = 0; tg < 2; ++tg) {
        float B1 = b1[tg], B2 = b2[tg]; int I1 = i1[tg];
#pragma unroll
        for (int mask = 16; mask <= 32; mask <<= 1) {
            float ob1 = __shfl_xor(B1, mask);
            float ob2 = __shfl_xor(B2, mask);
            int   oi  = __shfl_xor(I1, mask);
            bool take = (ob1 > B1) || (ob1 == B1 && oi < I1);
            B2 = fmaxf(fminf(ob1, B1), fmaxf(ob2, B2));
            I1 = take ? oi : I1;
            B1 = fmaxf(ob1, B1);
        }
        B1f[tg] = B1; B2f[tg] = B2; I1f[tg] = I1;   // replicated across quads
    }

    // token t (0..31) of this wave -> its index; lanes 0..31 own token lane
    int myidx;
    {
        int src = lane & 15;
        int v0 = __shfl(I1f[0], src);
        int v1 = __shfl(I1f[1], src);
        myidx = ((lane >> 4) & 1) ? v1 : v0;
    }

    // ---- ballot-driven exact fp32 rescan of near-ties (round-1 numerics) ----
#pragma unroll
    for (int tg = 0; tg < 2; ++tg) {
        unsigned long long msk =
            __ballot((lane < 16) && (B1f[tg] - B2f[tg] < 2e-3f));
        while (msk) {
            int mm = __ffsll((unsigned long long)msk) - 1;
            msk &= msk - 1;
            int tloc = tg * 16 + mm;              // token within this wave (0..31)
            const float4* xr = (const float4*)(x + (tok0 + tloc) * DIMD);
            float bv = 3e38f; int bi = 0;
            for (int j = 0; j < 16; ++j) {
                int k = lane * 16 + j;
                const float4* wr = (const float4*)(wfull + (size_t)k * DIMD);
                float s = 0.f;
#pragma unroll
                for (int i = 0; i < 16; ++i) {
                    float4 xv = xr[i], wv4 = wr[i];
                    s = fmaf(xv.x, wv4.x, s); s = fmaf(xv.y, wv4.y, s);
                    s = fmaf(xv.z, wv4.z, s); s = fmaf(xv.w, wv4.w, s);
                }
                float dv = fmaf(-2.f, s, e2_g[k]);
                if (dv < bv) { bv = dv; bi = k; }  // ties -> lower k
            }
#pragma unroll
            for (int mask2 = 1; mask2 <= 32; mask2 <<= 1) {
                float ov = __shfl_xor(bv, mask2);
                int   oi = __shfl_xor(bi, mask2);
                bool take = (ov < bv) || (ov == bv && oi < bi);
                bv = take ? ov : bv;
                bi = take ? oi : bi;
            }
            myidx = (lane == tloc) ? bi : myidx;
        }
    }

    // ---- outputs (nontemporal: pure streaming, keep L2 for wpk/e2n) ----
    if (lane < 32)
        __builtin_nontemporal_store((float)myidx,
                                    out + (size_t)MTOK * DIMD + tok0 + lane);

    // coalesced gather: per j, wave writes one contiguous 1KB segment;
    // codebook row read cooperatively (16 lanes per row, contiguous 256B)
    {
        float* obase = out + tok0 * DIMD;
#pragma unroll
        for (int j = 0; j < 8; ++j) {
            int srcl = j * 4 + (lane >> 4);        // token 0..31
            int gi   = __shfl(myidx, srcl);
            f32x4 v = *(const f32x4*)(wfull + (size_t)gi * DIMD + (lane & 15) * 4);
            __builtin_nontemporal_store(v, (f32x4*)(obase + j * 256 + lane * 4));
        }
    }
}

extern "C" void kernel_launch(void* const* d_in, const int* in_sizes, int n_in,
                              void* d_out, int out_size, void* d_ws, size_t ws_size,
                              hipStream_t stream) {
    const float* x = (const float*)d_in[0];
    const float* w = (const float*)d_in[1];
    float* out = (float*)d_out;

    // ws: [wpk 256K][e2n 4K][e2 4K]
    __bf16* wpk = (__bf16*)d_ws;
    float*  e2n = (float*)((char*)d_ws + 262144);
    float*  e2  = (float*)((char*)d_ws + 266240);

    prep_kernel<<<68, 256, 0, stream>>>(w, wpk, e2n, e2);
    vq_main<<<MTOK / TPB, 256, 0, stream>>>(x, w, wpk, e2n, e2, out);
}